// Round 1
// baseline (1707.442 us; speedup 1.0000x reference)
//
#include <hip/hip_runtime.h>
#include <hip/hip_bf16.h>

// Problem: B=8, O=1024, Q=2048, QD=1024, SG=1200
//   query  = query_in[B,O,QD] @ W[SG,QD]^T          -> [B,O,SG]   (GEMM1, NT)
//   scores = query[B,O,SG] @ context[B,Q,SG]^T      -> [B,O,Q]    (GEMM2, NT, batched)
//   weights= softmax(scores, axis=-1)                             (row softmax, 2048)
//   mix    = weights[B,O,Q] @ context[B,Q,SG]       -> [B,O,SG]   (GEMM3, NN, batched)
// Outputs concatenated: mix (9,830,400 f32) then weights (16,777,216 f32).

#define BM 128
#define BN 128
#define BK 16
#define PAD 4

// Generic fp32 tiled GEMM. A row-major [M,K] (M % 128 == 0, K % 16 == 0).
// BT=true : C[m,n] = sum_k A[m,k] * B[n,k]   (B row-major [N,K])
// BT=false: C[m,n] = sum_k A[m,k] * B[k,n]   (B row-major [K,N])
// N may be ragged but N % 4 == 0.
template <bool BT>
__global__ __launch_bounds__(256) void gemm_f32(
    const float* __restrict__ A, const float* __restrict__ Bm,
    float* __restrict__ C, int N, int K, int lda, int ldb, int ldc,
    long sA, long sB, long sC)
{
    const int bz = blockIdx.z;
    const float* Ab = A + (long)bz * sA;
    const float* Bb = Bm + (long)bz * sB;
    float* Cb = C + (long)bz * sC;

    __shared__ float As[BK][BM + PAD];
    __shared__ float Bs[BK][BN + PAD];

    const int t = threadIdx.x;
    const int tx = t & 15;   // 16 cols of threads -> 8 output cols each
    const int ty = t >> 4;   // 16 rows of threads -> 8 output rows each
    const int row0 = blockIdx.y * BM;
    const int col0 = blockIdx.x * BN;

    float acc[8][8];
#pragma unroll
    for (int i = 0; i < 8; ++i)
#pragma unroll
        for (int j = 0; j < 8; ++j) acc[i][j] = 0.f;

    for (int k0 = 0; k0 < K; k0 += BK) {
        // ---- stage A tile: 128 rows x 16 k, coalesced float4 along K, store transposed
#pragma unroll
        for (int i = 0; i < 2; ++i) {
            int L = t + i * 256;           // 0..511
            int r = L >> 2;                // 0..127
            int kq = (L & 3) << 2;         // 0,4,8,12
            float4 v = *(const float4*)(Ab + (long)(row0 + r) * lda + k0 + kq);
            As[kq + 0][r] = v.x; As[kq + 1][r] = v.y;
            As[kq + 2][r] = v.z; As[kq + 3][r] = v.w;
        }
        // ---- stage B tile
        if (BT) {
#pragma unroll
            for (int i = 0; i < 2; ++i) {
                int L = t + i * 256;
                int n = L >> 2;
                int kq = (L & 3) << 2;
                float4 v = make_float4(0.f, 0.f, 0.f, 0.f);
                if (col0 + n < N)
                    v = *(const float4*)(Bb + (long)(col0 + n) * ldb + k0 + kq);
                Bs[kq + 0][n] = v.x; Bs[kq + 1][n] = v.y;
                Bs[kq + 2][n] = v.z; Bs[kq + 3][n] = v.w;
            }
        } else {
#pragma unroll
            for (int i = 0; i < 2; ++i) {
                int L = t + i * 256;
                int kk = L >> 5;            // 0..15
                int nq = (L & 31) << 2;     // 0,4,...,124
                float4 v = make_float4(0.f, 0.f, 0.f, 0.f);
                if (col0 + nq < N)          // N%4==0, nq%4==0 -> full float4 in range
                    v = *(const float4*)(Bb + (long)(k0 + kk) * ldb + col0 + nq);
                *(float4*)&Bs[kk][nq] = v;
            }
        }
        __syncthreads();

#pragma unroll
        for (int kk = 0; kk < BK; ++kk) {
            float4 a0 = *(const float4*)&As[kk][ty * 8];
            float4 a1 = *(const float4*)&As[kk][ty * 8 + 4];
            float4 b0 = *(const float4*)&Bs[kk][tx * 8];
            float4 b1 = *(const float4*)&Bs[kk][tx * 8 + 4];
            float av[8] = {a0.x, a0.y, a0.z, a0.w, a1.x, a1.y, a1.z, a1.w};
            float bv[8] = {b0.x, b0.y, b0.z, b0.w, b1.x, b1.y, b1.z, b1.w};
#pragma unroll
            for (int i = 0; i < 8; ++i)
#pragma unroll
                for (int j = 0; j < 8; ++j)
                    acc[i][j] = fmaf(av[i], bv[j], acc[i][j]);
        }
        __syncthreads();
    }

#pragma unroll
    for (int i = 0; i < 8; ++i) {
        int gm = row0 + ty * 8 + i;
        float* crow = Cb + (long)gm * ldc;
        int gn = col0 + tx * 8;
        if (gn < N)   // N%4==0, gn%4==0 -> whole float4 valid
            *(float4*)(crow + gn) = make_float4(acc[i][0], acc[i][1], acc[i][2], acc[i][3]);
        if (gn + 4 < N)
            *(float4*)(crow + gn + 4) = make_float4(acc[i][4], acc[i][5], acc[i][6], acc[i][7]);
    }
}

// In-place softmax over rows of length 2048. One block (256 threads) per row.
__global__ __launch_bounds__(256) void softmax_2048(float* __restrict__ w)
{
    float* p = w + (long)blockIdx.x * 2048;
    const int t = threadIdx.x;
    float4 v0 = ((const float4*)p)[t];
    float4 v1 = ((const float4*)p)[t + 256];

    float m = fmaxf(fmaxf(fmaxf(v0.x, v0.y), fmaxf(v0.z, v0.w)),
                    fmaxf(fmaxf(v1.x, v1.y), fmaxf(v1.z, v1.w)));
#pragma unroll
    for (int off = 1; off < 64; off <<= 1) m = fmaxf(m, __shfl_xor(m, off));
    __shared__ float redm[4];
    __shared__ float reds[4];
    const int wave = t >> 6, lane = t & 63;
    if (lane == 0) redm[wave] = m;
    __syncthreads();
    m = fmaxf(fmaxf(redm[0], redm[1]), fmaxf(redm[2], redm[3]));

    float e[8];
    e[0] = __expf(v0.x - m); e[1] = __expf(v0.y - m);
    e[2] = __expf(v0.z - m); e[3] = __expf(v0.w - m);
    e[4] = __expf(v1.x - m); e[5] = __expf(v1.y - m);
    e[6] = __expf(v1.z - m); e[7] = __expf(v1.w - m);

    float s = ((e[0] + e[1]) + (e[2] + e[3])) + ((e[4] + e[5]) + (e[6] + e[7]));
#pragma unroll
    for (int off = 1; off < 64; off <<= 1) s += __shfl_xor(s, off);
    if (lane == 0) reds[wave] = s;
    __syncthreads();
    s = (reds[0] + reds[1]) + (reds[2] + reds[3]);

    const float inv = 1.0f / s;
    ((float4*)p)[t]       = make_float4(e[0] * inv, e[1] * inv, e[2] * inv, e[3] * inv);
    ((float4*)p)[t + 256] = make_float4(e[4] * inv, e[5] * inv, e[6] * inv, e[7] * inv);
}

extern "C" void kernel_launch(void* const* d_in, const int* in_sizes, int n_in,
                              void* d_out, int out_size, void* d_ws, size_t ws_size,
                              hipStream_t stream)
{
    const float* query_in   = (const float*)d_in[0]; // [8,1024,1024]
    const float* context_in = (const float*)d_in[1]; // [8,2048,1200]
    const float* W          = (const float*)d_in[2]; // [1200,1024]

    float* mix     = (float*)d_out;                  // [8,1024,1200]
    float* weights = (float*)d_out + 9830400LL;      // [8,1024,2048]
    float* query   = (float*)d_ws;                   // [8192,1200] scratch (39.3 MB)

    dim3 blk(256);

    // GEMM1: query[8192,1200] = query_in[8192,1024] @ W[1200,1024]^T
    gemm_f32<true><<<dim3((1200 + BN - 1) / BN, 8192 / BM, 1), blk, 0, stream>>>(
        query_in, W, query, 1200, 1024, 1024, 1024, 1200, 0, 0, 0);

    // GEMM2 (batched): scores[b][1024,2048] = query_b[1024,1200] @ context_b[2048,1200]^T
    gemm_f32<true><<<dim3(2048 / BN, 1024 / BM, 8), blk, 0, stream>>>(
        query, context_in, weights, 2048, 1200, 1200, 1200, 2048,
        1024L * 1200, 2048L * 1200, 1024L * 2048);

    // softmax in place over the weights buffer (8192 rows x 2048)
    softmax_2048<<<dim3(8192), blk, 0, stream>>>(weights);

    // GEMM3 (batched): mix[b][1024,1200] = weights_b[1024,2048] @ context_b[2048,1200]
    gemm_f32<false><<<dim3((1200 + BN - 1) / BN, 1024 / BM, 8), blk, 0, stream>>>(
        weights, context_in, mix, 1200, 2048, 2048, 1200, 1200,
        1024L * 2048, 2048L * 1200, 1024L * 1200);
}

// Round 2
// 574.247 us; speedup vs baseline: 2.9734x; 2.9734x over previous
//
#include <hip/hip_runtime.h>
#include <hip/hip_bf16.h>

// B=8, O=1024, Q=2048, QD=1024, SG=1200  (SG padded to 1216 for K%32==0)
//   GEMM1: query = query_in @ W^T        [8192,1024]x[1200,1024]^T  f16-split, out hi/lo f16
//   GEMM2: scores = query @ ctx^T        per-b [1024,1216]x[2048,1216]^T f16-split, out f32
//   softmax rows of 2048 (in-place in d_out) + f16 copy of weights
//   GEMM3: mix = weights @ ctx           via NT with pre-transposed ctxT, pure f16, out f32
// Outputs: mix (8*1024*1200 f32) then weights (8*1024*2048 f32).
// WS requirement: ~231 MB (see layout in kernel_launch).

typedef _Float16 half8 __attribute__((ext_vector_type(8)));
typedef _Float16 half4v __attribute__((ext_vector_type(4)));
typedef float    f32x4 __attribute__((ext_vector_type(4)));

#define AS1C(p) ((const __attribute__((address_space(1))) void*)(p))
#define AS3(p)  ((__attribute__((address_space(3))) void*)(p))

// ---- stage a 128x32-f16 tile (rows row0.., k-cols k0..k0+31) into an 8KB LDS array.
// LDS dest is linear (global_load_lds requirement); bank-conflict-free read is achieved
// by pre-swizzling the GLOBAL source chunk: chunk koff of row r lands at slot koff^((r>>1)&3).
__device__ __forceinline__ void stage_tile(const _Float16* __restrict__ X, _Float16* s,
                                           int t, long row0, long rowmax, int ld, int k0)
{
#pragma unroll
    for (int j = 0; j < 2; ++j) {
        const int L = t + 256 * j;            // 0..511 : L*16B = LDS byte offset
        const int r = L >> 2;                 // LDS row 0..127
        const int slot = L & 3;               // 16B slot within row
        const int koff = slot ^ ((r >> 1) & 3);
        long grow = row0 + r; if (grow > rowmax) grow = rowmax;  // clamp ragged N
        const _Float16* src = X + grow * (long)ld + k0 + koff * 8;
        _Float16* dst = s + (long)((t & ~63) + 256 * j) * 8;     // wave-uniform base
        __builtin_amdgcn_global_load_lds(AS1C(src), AS3(dst), 16, 0, 0);
    }
}

// swizzled fragment read: 8 f16 along K for (local row, k-chunk kslot)
__device__ __forceinline__ half8 frag(const _Float16* s, int row, int kslot)
{
    return *(const half8*)(s + row * 32 + ((kslot ^ ((row >> 1) & 3)) << 3));
}

// Unified NT MFMA GEMM. A row-major [M,K] f16 (hi[,lo]), B row-major [N,K] f16 (hi[,lo]).
// SPLIT: acc += Ah*Bh + Ah*Bl + Al*Bh. OUT16: write (hi,lo) f16 pair w/ zero-padded cols
// up to ldc; else write f32, cols < N.
template<bool SPLIT, bool OUT16>
__global__ __launch_bounds__(256) void gemm16(
    const _Float16* __restrict__ Ah, const _Float16* __restrict__ Al,
    const _Float16* __restrict__ Bh, const _Float16* __restrict__ Bl,
    float* __restrict__ Cf, _Float16* __restrict__ Ch, _Float16* __restrict__ Cl,
    int N, int K, int lda, int ldb, int ldc,
    long sA, long sB, long sC)
{
    const int t = threadIdx.x;
    const int bz = blockIdx.z;
    const _Float16* A_h = Ah + bz * sA;
    const _Float16* B_h = Bh + bz * sB;
    const _Float16* A_l = SPLIT ? (Al + bz * sA) : nullptr;
    const _Float16* B_l = SPLIT ? (Bl + bz * sB) : nullptr;

    __shared__ __align__(16) _Float16 sAh[128 * 32];
    __shared__ __align__(16) _Float16 sBh[128 * 32];
    __shared__ __align__(16) _Float16 sAl[SPLIT ? 128 * 32 : 8];
    __shared__ __align__(16) _Float16 sBl[SPLIT ? 128 * 32 : 8];

    const long row0 = (long)blockIdx.y * 128;   // batch-local M offset
    const int  col0 = blockIdx.x * 128;

    const int wid = t >> 6, lane = t & 63;
    const int wm = (wid >> 1) * 64, wn = (wid & 1) * 64;
    const int fr = lane & 15, kslot = lane >> 4;

    f32x4 acc[4][4];
#pragma unroll
    for (int i = 0; i < 4; ++i)
#pragma unroll
        for (int j = 0; j < 4; ++j) acc[i][j] = (f32x4){0.f, 0.f, 0.f, 0.f};

    for (int k0 = 0; k0 < K; k0 += 32) {
        __syncthreads();   // previous tile fully consumed
        stage_tile(A_h, sAh, t, row0, row0 + 127, lda, k0);
        stage_tile(B_h, sBh, t, col0, N - 1, ldb, k0);
        if (SPLIT) {
            stage_tile(A_l, sAl, t, row0, row0 + 127, lda, k0);
            stage_tile(B_l, sBl, t, col0, N - 1, ldb, k0);
        }
        __syncthreads();   // drains vmcnt (compiler-inserted) -> tile resident

        half8 a_h[4], b_h[4], a_l[4], b_l[4];
#pragma unroll
        for (int i = 0; i < 4; ++i) {
            a_h[i] = frag(sAh, wm + i * 16 + fr, kslot);
            b_h[i] = frag(sBh, wn + i * 16 + fr, kslot);
            if (SPLIT) {
                a_l[i] = frag(sAl, wm + i * 16 + fr, kslot);
                b_l[i] = frag(sBl, wn + i * 16 + fr, kslot);
            }
        }
#pragma unroll
        for (int mi = 0; mi < 4; ++mi)
#pragma unroll
            for (int ni = 0; ni < 4; ++ni) {
                acc[mi][ni] = __builtin_amdgcn_mfma_f32_16x16x32_f16(a_h[mi], b_h[ni], acc[mi][ni], 0, 0, 0);
                if (SPLIT) {
                    acc[mi][ni] = __builtin_amdgcn_mfma_f32_16x16x32_f16(a_h[mi], b_l[ni], acc[mi][ni], 0, 0, 0);
                    acc[mi][ni] = __builtin_amdgcn_mfma_f32_16x16x32_f16(a_l[mi], b_h[ni], acc[mi][ni], 0, 0, 0);
                }
            }
    }

    // C/D layout (m89-verified): col = lane&15, row = (lane>>4)*4 + reg
    const int r4 = (lane >> 4) * 4;
    float* C_f = OUT16 ? nullptr : (Cf + bz * sC);
#pragma unroll
    for (int mi = 0; mi < 4; ++mi)
#pragma unroll
        for (int ni = 0; ni < 4; ++ni) {
            const int colg = col0 + wn + ni * 16 + fr;
#pragma unroll
            for (int r = 0; r < 4; ++r) {
                const long rowg = row0 + wm + mi * 16 + r4 + r;
                const float v = acc[mi][ni][r];
                if (OUT16) {
                    if (colg < ldc) {                 // ldc = padded width (zeros in pad)
                        const float vv = (colg < N) ? v : 0.f;
                        const _Float16 hi = (_Float16)vv;
                        const _Float16 lo = (_Float16)(vv - (float)hi);
                        Ch[rowg * ldc + colg] = hi;
                        Cl[rowg * ldc + colg] = lo;
                    }
                } else {
                    if (colg < N) C_f[rowg * (long)ldc + colg] = v;
                }
            }
        }
}

// fp32 -> (hi,lo) f16 split, with zero padding cin..cout. Vec4 per thread, grid-stride.
__global__ __launch_bounds__(256) void cvt_split(const float* __restrict__ X,
    _Float16* __restrict__ H, _Float16* __restrict__ L,
    long total4, int cin4, int cout4)
{
    for (long i = (long)blockIdx.x * 256 + threadIdx.x; i < total4; i += (long)gridDim.x * 256) {
        const long r = i / cout4;
        const int  c = (int)(i - r * cout4);
        float4 v = make_float4(0.f, 0.f, 0.f, 0.f);
        if (c < cin4) v = *(const float4*)(X + (r * cin4 + c) * 4);
        const _Float16 h0 = (_Float16)v.x, h1 = (_Float16)v.y, h2 = (_Float16)v.z, h3 = (_Float16)v.w;
        const _Float16 l0 = (_Float16)(v.x - (float)h0), l1 = (_Float16)(v.y - (float)h1);
        const _Float16 l2 = (_Float16)(v.z - (float)h2), l3 = (_Float16)(v.w - (float)h3);
        *(half4v*)(H + (r * cout4 + c) * 4) = (half4v){h0, h1, h2, h3};
        *(half4v*)(L + (r * cout4 + c) * 4) = (half4v){l0, l1, l2, l3};
    }
}

// ctx [8][2048][1200] f32 -> ctxT [8][1200][2048] f16 (pure f16 for GEMM3's B)
__global__ __launch_bounds__(256) void tcvt(const float* __restrict__ X, _Float16* __restrict__ Y)
{
    const int b = blockIdx.z;
    const float* Xb = X + (long)b * 2048 * 1200;
    _Float16* Yb = Y + (long)b * 1200 * 2048;
    __shared__ _Float16 tl[32][33];
    const int tx = threadIdx.x & 31, ty = threadIdx.x >> 5;
    const int s0 = blockIdx.x * 32, q0 = blockIdx.y * 32;
#pragma unroll
    for (int p = 0; p < 4; ++p) {
        const int q = q0 + ty + p * 8, s = s0 + tx;
        const float v = (s < 1200) ? Xb[(long)q * 1200 + s] : 0.f;
        tl[tx][ty + p * 8] = (_Float16)v;
    }
    __syncthreads();
#pragma unroll
    for (int p = 0; p < 4; ++p) {
        const int s = s0 + ty + p * 8;
        if (s < 1200) Yb[(long)s * 2048 + q0 + tx] = tl[ty + p * 8][tx];
    }
}

// in-place row softmax (2048) + f16 copy for GEMM3
__global__ __launch_bounds__(256) void softmax_k(float* __restrict__ w, _Float16* __restrict__ w16)
{
    float* p = w + (long)blockIdx.x * 2048;
    half4v* p16 = (half4v*)(w16 + (long)blockIdx.x * 2048);
    const int t = threadIdx.x;
    float4 v0 = ((const float4*)p)[t];
    float4 v1 = ((const float4*)p)[t + 256];

    float m = fmaxf(fmaxf(fmaxf(v0.x, v0.y), fmaxf(v0.z, v0.w)),
                    fmaxf(fmaxf(v1.x, v1.y), fmaxf(v1.z, v1.w)));
#pragma unroll
    for (int off = 1; off < 64; off <<= 1) m = fmaxf(m, __shfl_xor(m, off));
    __shared__ float redm[4], reds[4];
    const int wave = t >> 6, lane = t & 63;
    if (lane == 0) redm[wave] = m;
    __syncthreads();
    m = fmaxf(fmaxf(redm[0], redm[1]), fmaxf(redm[2], redm[3]));

    float e[8];
    e[0] = __expf(v0.x - m); e[1] = __expf(v0.y - m);
    e[2] = __expf(v0.z - m); e[3] = __expf(v0.w - m);
    e[4] = __expf(v1.x - m); e[5] = __expf(v1.y - m);
    e[6] = __expf(v1.z - m); e[7] = __expf(v1.w - m);

    float s = ((e[0] + e[1]) + (e[2] + e[3])) + ((e[4] + e[5]) + (e[6] + e[7]));
#pragma unroll
    for (int off = 1; off < 64; off <<= 1) s += __shfl_xor(s, off);
    if (lane == 0) reds[wave] = s;
    __syncthreads();
    s = (reds[0] + reds[1]) + (reds[2] + reds[3]);

    const float inv = 1.0f / s;
    float o0 = e[0] * inv, o1 = e[1] * inv, o2 = e[2] * inv, o3 = e[3] * inv;
    float o4 = e[4] * inv, o5 = e[5] * inv, o6 = e[6] * inv, o7 = e[7] * inv;
    ((float4*)p)[t]       = make_float4(o0, o1, o2, o3);
    ((float4*)p)[t + 256] = make_float4(o4, o5, o6, o7);
    p16[t]       = (half4v){(_Float16)o0, (_Float16)o1, (_Float16)o2, (_Float16)o3};
    p16[t + 256] = (half4v){(_Float16)o4, (_Float16)o5, (_Float16)o6, (_Float16)o7};
}

extern "C" void kernel_launch(void* const* d_in, const int* in_sizes, int n_in,
                              void* d_out, int out_size, void* d_ws, size_t ws_size,
                              hipStream_t stream)
{
    const float* query_in = (const float*)d_in[0]; // [8,1024,1024]
    const float* context  = (const float*)d_in[1]; // [8,2048,1200]
    const float* W        = (const float*)d_in[2]; // [1200,1024]

    float* mix    = (float*)d_out;                 // [8,1024,1200]
    float* scores = (float*)d_out + 9830400LL;     // [8,1024,2048] -> softmax in place

    // ws layout (halfs); total 230,883,328 bytes (~220 MB)
    _Float16* qh  = (_Float16*)d_ws;               // query_in hi  [8192,1024]
    _Float16* ql  = qh  + 8388608;                 // query_in lo
    _Float16* wh  = ql  + 8388608;                 // W hi         [1200,1024]
    _Float16* wl  = wh  + 1228800;                 // W lo
    _Float16* ch  = wl  + 1228800;                 // ctx hi       [16384,1216] (zero-pad 1200..1215)
    _Float16* cl  = ch  + 19922944;                // ctx lo
    _Float16* ct  = cl  + 19922944;                // ctxT f16     [8][1200][2048]
    _Float16* qeh = ct  + 19660800;                // query hi     [8192,1216]
    _Float16* qel = qeh + 9961472;                 // query lo
    _Float16* w16 = qel + 9961472;                 // weights f16  [8192,2048]

    dim3 blk(256);

    cvt_split<<<2048, blk, 0, stream>>>(query_in, qh, ql, 8192L * 256, 256, 256);
    cvt_split<<<512,  blk, 0, stream>>>(W,        wh, wl, 1200L * 256, 256, 256);
    cvt_split<<<2048, blk, 0, stream>>>(context,  ch, cl, 16384L * 304, 300, 304);
    tcvt<<<dim3(38, 64, 8), blk, 0, stream>>>(context, ct);

    // GEMM1: query(hi/lo)[8192,1216] = qin[8192,1024] @ W[1200,1024]^T  (split, out f16 pair)
    gemm16<true, true><<<dim3(10, 64, 1), blk, 0, stream>>>(
        qh, ql, wh, wl, nullptr, qeh, qel,
        1200, 1024, 1024, 1024, 1216, 0, 0, 0);

    // GEMM2: scores[b][1024,2048] = query_b[1024,1216] @ ctx_b[2048,1216]^T  (split, out f32)
    gemm16<true, false><<<dim3(16, 8, 8), blk, 0, stream>>>(
        qeh, qel, ch, cl, scores, nullptr, nullptr,
        2048, 1216, 1216, 1216, 2048, 1024L * 1216, 2048L * 1216, 1024L * 2048);

    softmax_k<<<dim3(8192), blk, 0, stream>>>(scores, w16);

    // GEMM3: mix[b][1024,1200] = w16_b[1024,2048] @ ctxT_b[1200,2048]^T  (pure f16, out f32)
    gemm16<false, false><<<dim3(10, 8, 8), blk, 0, stream>>>(
        w16, nullptr, ct, nullptr, mix, nullptr, nullptr,
        1200, 2048, 2048, 2048, 1200, 1024L * 2048, 1200L * 2048, 1024L * 1200);
}

// Round 5
// 532.825 us; speedup vs baseline: 3.2045x; 1.0777x over previous
//
#include <hip/hip_runtime.h>
#include <hip/hip_bf16.h>

// B=8, O=1024, Q=2048, QD=1024, SG=1200  (SG padded to 1216 for K%32==0)
//   GEMM1: query = query_in @ W^T        [8192,1024]x[1200,1024]^T  f16-split, out hi/lo f16
//   GEMM2: scores = query @ ctx^T        per-b [1024,1216]x[2048,1216]^T f16-split, out f32
//   softmax rows of 2048 (in-place in d_out) + f16 copy of weights
//   GEMM3: mix = weights @ ctx           via NT with pre-transposed ctxT, pure f16, out f32
// GEMM schedule: 2-phase double-buffered (prefetch k+1 issued BEFORE compute of k,
// single __syncthreads per K-step whose implicit vmcnt(0) drain lands after the MFMAs).

typedef _Float16 half8 __attribute__((ext_vector_type(8)));
typedef _Float16 half4v __attribute__((ext_vector_type(4)));
typedef float    f32x4 __attribute__((ext_vector_type(4)));

#define AS1C(p) ((const __attribute__((address_space(1))) void*)(p))
#define AS3(p)  ((__attribute__((address_space(3))) void*)(p))

// ---- stage a 128x32-f16 tile (rows row0.., k-cols k0..k0+31) into an 8KB LDS array.
// LDS dest linear (global_load_lds requirement); conflict-free ds_read achieved by
// pre-swizzling the GLOBAL source chunk: chunk koff of row r lands at slot koff^((r>>1)&3).
__device__ __forceinline__ void stage_tile(const _Float16* __restrict__ X, _Float16* s,
                                           int t, long row0, long rowmax, int ld, int k0)
{
#pragma unroll
    for (int j = 0; j < 2; ++j) {
        const int L = t + 256 * j;            // 0..511 : L*16B = LDS byte offset
        const int r = L >> 2;                 // LDS row 0..127
        const int slot = L & 3;               // 16B slot within row
        const int koff = slot ^ ((r >> 1) & 3);
        long grow = row0 + r; if (grow > rowmax) grow = rowmax;  // clamp ragged N
        const _Float16* src = X + grow * (long)ld + k0 + koff * 8;
        _Float16* dst = s + (long)((t & ~63) + 256 * j) * 8;     // wave-uniform base
        __builtin_amdgcn_global_load_lds(AS1C(src), AS3(dst), 16, 0, 0);
    }
}

// swizzled fragment read: 8 f16 along K for (local row, k-chunk kslot)
__device__ __forceinline__ half8 frag(const _Float16* s, int row, int kslot)
{
    return *(const half8*)(s + row * 32 + ((kslot ^ ((row >> 1) & 3)) << 3));
}

// Unified NT MFMA GEMM, 128x128 tile, BK=32, double-buffered 2-phase pipeline.
// A row-major [M,K] f16 (hi[,lo]), B row-major [N,K] f16 (hi[,lo]).
// SPLIT: acc += Ah*Bh + Ah*Bl + Al*Bh. OUT16: write (hi,lo) f16 pair, cols zero-padded
// up to ldc; else write f32, cols < N.
template<bool SPLIT, bool OUT16>
__global__ __launch_bounds__(256) void gemm16(
    const _Float16* __restrict__ Ah, const _Float16* __restrict__ Al,
    const _Float16* __restrict__ Bh, const _Float16* __restrict__ Bl,
    float* __restrict__ Cf, _Float16* __restrict__ Ch, _Float16* __restrict__ Cl,
    int N, int K, int lda, int ldb, int ldc,
    long sA, long sB, long sC)
{
    const int t = threadIdx.x;
    const int bz = blockIdx.z;
    const _Float16* A_h = Ah + bz * sA;
    const _Float16* B_h = Bh + bz * sB;
    const _Float16* A_l = SPLIT ? (Al + bz * sA) : nullptr;
    const _Float16* B_l = SPLIT ? (Bl + bz * sB) : nullptr;

    __shared__ __align__(16) _Float16 sAh[2][128 * 32];
    __shared__ __align__(16) _Float16 sBh[2][128 * 32];
    __shared__ __align__(16) _Float16 sAl[SPLIT ? 2 : 1][SPLIT ? 128 * 32 : 8];
    __shared__ __align__(16) _Float16 sBl[SPLIT ? 2 : 1][SPLIT ? 128 * 32 : 8];

    const long row0 = (long)blockIdx.y * 128;   // batch-local M offset
    const int  col0 = blockIdx.x * 128;

    const int wid = t >> 6, lane = t & 63;
    const int wm = (wid >> 1) * 64, wn = (wid & 1) * 64;
    const int fr = lane & 15, kslot = lane >> 4;

    f32x4 acc[4][4];
#pragma unroll
    for (int i = 0; i < 4; ++i)
#pragma unroll
        for (int j = 0; j < 4; ++j) acc[i][j] = (f32x4){0.f, 0.f, 0.f, 0.f};

    // prologue: stage tile 0 into buffer 0
    stage_tile(A_h, sAh[0], t, row0, row0 + 127, lda, 0);
    stage_tile(B_h, sBh[0], t, col0, N - 1, ldb, 0);
    if (SPLIT) {
        stage_tile(A_l, sAl[0], t, row0, row0 + 127, lda, 0);
        stage_tile(B_l, sBl[0], t, col0, N - 1, ldb, 0);
    }
    __syncthreads();

    int cur = 0;
    for (int k0 = 0; k0 < K; k0 += 32) {
        // issue prefetch of next K-tile into the other buffer BEFORE computing this one
        if (k0 + 32 < K) {
            const int nxt = cur ^ 1, kn = k0 + 32;
            stage_tile(A_h, sAh[nxt], t, row0, row0 + 127, lda, kn);
            stage_tile(B_h, sBh[nxt], t, col0, N - 1, ldb, kn);
            if (SPLIT) {
                stage_tile(A_l, sAl[nxt], t, row0, row0 + 127, lda, kn);
                stage_tile(B_l, sBl[nxt], t, col0, N - 1, ldb, kn);
            }
        }

        half8 a_h[4], b_h[4], a_l[4], b_l[4];
#pragma unroll
        for (int i = 0; i < 4; ++i) {
            a_h[i] = frag(sAh[cur], wm + i * 16 + fr, kslot);
            b_h[i] = frag(sBh[cur], wn + i * 16 + fr, kslot);
            if (SPLIT) {
                a_l[i] = frag(sAl[cur], wm + i * 16 + fr, kslot);
                b_l[i] = frag(sBl[cur], wn + i * 16 + fr, kslot);
            }
        }
#pragma unroll
        for (int mi = 0; mi < 4; ++mi)
#pragma unroll
            for (int ni = 0; ni < 4; ++ni) {
                acc[mi][ni] = __builtin_amdgcn_mfma_f32_16x16x32_f16(a_h[mi], b_h[ni], acc[mi][ni], 0, 0, 0);
                if (SPLIT) {
                    acc[mi][ni] = __builtin_amdgcn_mfma_f32_16x16x32_f16(a_h[mi], b_l[ni], acc[mi][ni], 0, 0, 0);
                    acc[mi][ni] = __builtin_amdgcn_mfma_f32_16x16x32_f16(a_l[mi], b_h[ni], acc[mi][ni], 0, 0, 0);
                }
            }

        // single barrier per K-step: implicit vmcnt(0)+lgkmcnt(0) drain makes the
        // prefetched buffer resident for every wave before the swap.
        __syncthreads();
        cur ^= 1;
    }

    // C/D layout (m89-verified): col = lane&15, row = (lane>>4)*4 + reg
    const int r4 = (lane >> 4) * 4;
    float* C_f = OUT16 ? nullptr : (Cf + bz * sC);
#pragma unroll
    for (int mi = 0; mi < 4; ++mi)
#pragma unroll
        for (int ni = 0; ni < 4; ++ni) {
            const int colg = col0 + wn + ni * 16 + fr;
#pragma unroll
            for (int r = 0; r < 4; ++r) {
                const long rowg = row0 + wm + mi * 16 + r4 + r;
                const float v = acc[mi][ni][r];
                if (OUT16) {
                    if (colg < ldc) {                 // ldc = padded width (zeros in pad)
                        const float vv = (colg < N) ? v : 0.f;
                        const _Float16 hi = (_Float16)vv;
                        const _Float16 lo = (_Float16)(vv - (float)hi);
                        Ch[rowg * ldc + colg] = hi;
                        Cl[rowg * ldc + colg] = lo;
                    }
                } else {
                    if (colg < N) C_f[rowg * (long)ldc + colg] = v;
                }
            }
        }
}

// fused fp32 -> (hi,lo) f16 split for query_in and W (no padding, both widths %4==0)
__global__ __launch_bounds__(256) void qw_cvt(
    const float* __restrict__ Q, _Float16* __restrict__ QH, _Float16* __restrict__ QL,
    const float* __restrict__ Wt, _Float16* __restrict__ WH, _Float16* __restrict__ WL)
{
    const long NQ = 8192L * 1024 / 4;
    const long NT = NQ + 1200L * 1024 / 4;
    for (long i = (long)blockIdx.x * 256 + threadIdx.x; i < NT; i += (long)gridDim.x * 256) {
        const float* src; _Float16 *dh, *dl; long j;
        if (i < NQ) { j = i; src = Q; dh = QH; dl = QL; }
        else        { j = i - NQ; src = Wt; dh = WH; dl = WL; }
        float4 v = *(const float4*)(src + j * 4);
        const _Float16 h0 = (_Float16)v.x, h1 = (_Float16)v.y, h2 = (_Float16)v.z, h3 = (_Float16)v.w;
        const _Float16 l0 = (_Float16)(v.x - (float)h0), l1 = (_Float16)(v.y - (float)h1);
        const _Float16 l2 = (_Float16)(v.z - (float)h2), l3 = (_Float16)(v.w - (float)h3);
        *(half4v*)(dh + j * 4) = (half4v){h0, h1, h2, h3};
        *(half4v*)(dl + j * 4) = (half4v){l0, l1, l2, l3};
    }
}

// fused ctx prep: one read of ctx f32 [8][2048][1200] ->
//   H,L [8][2048][1216] (hi/lo split, zero-pad cols 1200..1215)
//   T   [8][1200][2048] f16 transpose (hi only, for GEMM3's B)
__global__ __launch_bounds__(256) void ctx_prep(const float* __restrict__ X,
    _Float16* __restrict__ H, _Float16* __restrict__ L, _Float16* __restrict__ T)
{
    const int b = blockIdx.z;
    const float* Xb = X + (long)b * 2048 * 1200;
    _Float16* Hb = H + (long)b * 2048 * 1216;
    _Float16* Lb = L + (long)b * 2048 * 1216;
    _Float16* Tb = T + (long)b * 1200 * 2048;
    __shared__ _Float16 tl[32][33];
    const int tx = threadIdx.x & 31, ty = threadIdx.x >> 5;
    const int s0 = blockIdx.x * 32, q0 = blockIdx.y * 32;   // s0 < 1216, q0 < 2048
#pragma unroll
    for (int p = 0; p < 4; ++p) {
        const int q = q0 + ty + p * 8, s = s0 + tx;
        const float v = (s < 1200) ? Xb[(long)q * 1200 + s] : 0.f;
        const _Float16 hi = (_Float16)v;
        Hb[(long)q * 1216 + s] = hi;
        Lb[(long)q * 1216 + s] = (_Float16)(v - (float)hi);
        tl[tx][ty + p * 8] = hi;
    }
    __syncthreads();
#pragma unroll
    for (int p = 0; p < 4; ++p) {
        const int s = s0 + ty + p * 8;
        if (s < 1200) Tb[(long)s * 2048 + q0 + tx] = tl[ty + p * 8][tx];
    }
}

// in-place row softmax (2048) + f16 copy for GEMM3
__global__ __launch_bounds__(256) void softmax_k(float* __restrict__ w, _Float16* __restrict__ w16)
{
    float* p = w + (long)blockIdx.x * 2048;
    half4v* p16 = (half4v*)(w16 + (long)blockIdx.x * 2048);
    const int t = threadIdx.x;
    float4 v0 = ((const float4*)p)[t];
    float4 v1 = ((const float4*)p)[t + 256];

    float m = fmaxf(fmaxf(fmaxf(v0.x, v0.y), fmaxf(v0.z, v0.w)),
                    fmaxf(fmaxf(v1.x, v1.y), fmaxf(v1.z, v1.w)));
#pragma unroll
    for (int off = 1; off < 64; off <<= 1) m = fmaxf(m, __shfl_xor(m, off));
    __shared__ float redm[4], reds[4];
    const int wave = t >> 6, lane = t & 63;
    if (lane == 0) redm[wave] = m;
    __syncthreads();
    m = fmaxf(fmaxf(redm[0], redm[1]), fmaxf(redm[2], redm[3]));

    float e[8];
    e[0] = __expf(v0.x - m); e[1] = __expf(v0.y - m);
    e[2] = __expf(v0.z - m); e[3] = __expf(v0.w - m);
    e[4] = __expf(v1.x - m); e[5] = __expf(v1.y - m);
    e[6] = __expf(v1.z - m); e[7] = __expf(v1.w - m);

    float s = ((e[0] + e[1]) + (e[2] + e[3])) + ((e[4] + e[5]) + (e[6] + e[7]));
#pragma unroll
    for (int off = 1; off < 64; off <<= 1) s += __shfl_xor(s, off);
    if (lane == 0) reds[wave] = s;
    __syncthreads();
    s = (reds[0] + reds[1]) + (reds[2] + reds[3]);

    const float inv = 1.0f / s;
    float o0 = e[0] * inv, o1 = e[1] * inv, o2 = e[2] * inv, o3 = e[3] * inv;
    float o4 = e[4] * inv, o5 = e[5] * inv, o6 = e[6] * inv, o7 = e[7] * inv;
    ((float4*)p)[t]       = make_float4(o0, o1, o2, o3);
    ((float4*)p)[t + 256] = make_float4(o4, o5, o6, o7);
    p16[t]       = (half4v){(_Float16)o0, (_Float16)o1, (_Float16)o2, (_Float16)o3};
    p16[t + 256] = (half4v){(_Float16)o4, (_Float16)o5, (_Float16)o6, (_Float16)o7};
}

extern "C" void kernel_launch(void* const* d_in, const int* in_sizes, int n_in,
                              void* d_out, int out_size, void* d_ws, size_t ws_size,
                              hipStream_t stream)
{
    const float* query_in = (const float*)d_in[0]; // [8,1024,1024]
    const float* context  = (const float*)d_in[1]; // [8,2048,1200]
    const float* W        = (const float*)d_in[2]; // [1200,1024]

    float* mix    = (float*)d_out;                 // [8,1024,1200]
    float* scores = (float*)d_out + 9830400LL;     // [8,1024,2048] -> softmax in place

    // ws layout (halfs); ~220 MB
    _Float16* qh  = (_Float16*)d_ws;               // query_in hi  [8192,1024]
    _Float16* ql  = qh  + 8388608;                 // query_in lo
    _Float16* wh  = ql  + 8388608;                 // W hi         [1200,1024]
    _Float16* wl  = wh  + 1228800;                 // W lo
    _Float16* ch  = wl  + 1228800;                 // ctx hi       [16384,1216] (zero-pad 1200..1215)
    _Float16* cl  = ch  + 19922944;                // ctx lo
    _Float16* ct  = cl  + 19922944;                // ctxT f16     [8][1200][2048]
    _Float16* qeh = ct  + 19660800;                // query hi     [8192,1216]
    _Float16* qel = qeh + 9961472;                 // query lo
    _Float16* w16 = qel + 9961472;                 // weights f16  [8192,2048]

    dim3 blk(256);

    qw_cvt<<<2400, blk, 0, stream>>>(query_in, qh, ql, W, wh, wl);
    ctx_prep<<<dim3(38, 64, 8), blk, 0, stream>>>(context, ch, cl, ct);

    // GEMM1: query(hi/lo)[8192,1216] = qin[8192,1024] @ W[1200,1024]^T  (split, out f16 pair)
    gemm16<true, true><<<dim3(10, 64, 1), blk, 0, stream>>>(
        qh, ql, wh, wl, nullptr, qeh, qel,
        1200, 1024, 1024, 1024, 1216, 0, 0, 0);

    // GEMM2: scores[b][1024,2048] = query_b[1024,1216] @ ctx_b[2048,1216]^T  (split, out f32)
    gemm16<true, false><<<dim3(16, 8, 8), blk, 0, stream>>>(
        qeh, qel, ch, cl, scores, nullptr, nullptr,
        2048, 1216, 1216, 1216, 2048, 1024L * 1216, 2048L * 1216, 1024L * 2048);

    softmax_k<<<dim3(8192), blk, 0, stream>>>(scores, w16);

    // GEMM3: mix[b][1024,1200] = w16_b[1024,2048] @ ctxT_b[1200,2048]^T  (pure f16, out f32)
    gemm16<false, false><<<dim3(10, 8, 8), blk, 0, stream>>>(
        w16, nullptr, ct, nullptr, mix, nullptr, nullptr,
        1200, 2048, 2048, 2048, 1200, 1024L * 2048, 1200L * 2048, 1024L * 1200);
}

// Round 6
// 521.310 us; speedup vs baseline: 3.2753x; 1.0221x over previous
//
#include <hip/hip_runtime.h>
#include <hip/hip_bf16.h>

// B=8, O=1024, Q=2048, QD=1024, SG=1200  (SG padded to 1216 for K%32==0)
//   GEMM1: query = query_in @ W^T        f16-split 3-term, 128² 2-phase, out hi/lo f16
//   GEMM2: scores = query @ ctx^T        f16-split 3-term, 256² 8-wave counted-vmcnt pipeline
//   softmax rows of 2048 (in-place in d_out) + f16 copy of weights
//   GEMM3: mix = weights @ ctx           pure f16 NT via pre-transposed ctxT, 128² 2-phase

typedef _Float16 half8 __attribute__((ext_vector_type(8)));
typedef _Float16 half4v __attribute__((ext_vector_type(4)));
typedef float    f32x4 __attribute__((ext_vector_type(4)));

#define AS1C(p) ((const __attribute__((address_space(1))) void*)(p))
#define AS3(p)  ((__attribute__((address_space(3))) void*)(p))

#define WAITV8() do { asm volatile("s_waitcnt vmcnt(8)" ::: "memory"); __builtin_amdgcn_sched_barrier(0); } while(0)
#define WAITV4() do { asm volatile("s_waitcnt vmcnt(4)" ::: "memory"); __builtin_amdgcn_sched_barrier(0); } while(0)
#define WAITV0() do { asm volatile("s_waitcnt vmcnt(0)" ::: "memory"); __builtin_amdgcn_sched_barrier(0); } while(0)
#define WAITL0() do { asm volatile("s_waitcnt lgkmcnt(0)" ::: "memory"); __builtin_amdgcn_sched_barrier(0); } while(0)

// ======================= shared staging helpers =======================
// LDS dest linear (global_load_lds requirement); conflict-free ds_read via
// pre-swizzled GLOBAL source: chunk koff of row r lands at slot koff^((r>>1)&3).

// 128 rows x 32 f16 (8 KB), 256 threads
__device__ __forceinline__ void stage_tile(const _Float16* __restrict__ X, _Float16* s,
                                           int t, long row0, long rowmax, int ld, int k0)
{
#pragma unroll
    for (int j = 0; j < 2; ++j) {
        const int L = t + 256 * j;
        const int r = L >> 2;
        const int slot = L & 3;
        const int koff = slot ^ ((r >> 1) & 3);
        long grow = row0 + r; if (grow > rowmax) grow = rowmax;
        const _Float16* src = X + grow * (long)ld + k0 + koff * 8;
        _Float16* dst = s + (long)((t & ~63) + 256 * j) * 8;
        __builtin_amdgcn_global_load_lds(AS1C(src), AS3(dst), 16, 0, 0);
    }
}

// 256 rows x 32 f16 (16 KB), 512 threads, no row guard (exact dims)
__device__ __forceinline__ void stage256(const _Float16* __restrict__ X, _Float16* s,
                                         int t, long row0, int ld, int k0)
{
#pragma unroll
    for (int j = 0; j < 2; ++j) {
        const int L = t + 512 * j;            // 0..1023
        const int r = L >> 2;                 // 0..255
        const int slot = L & 3;
        const int koff = slot ^ ((r >> 1) & 3);
        const _Float16* src = X + (row0 + r) * (long)ld + k0 + koff * 8;
        _Float16* dst = s + (long)((t & ~63) + 512 * j) * 8;
        __builtin_amdgcn_global_load_lds(AS1C(src), AS3(dst), 16, 0, 0);
    }
}

// swizzled fragment read: 8 f16 along K for (local row, k-chunk kslot)
__device__ __forceinline__ half8 frag(const _Float16* s, int row, int kslot)
{
    return *(const half8*)(s + row * 32 + ((kslot ^ ((row >> 1) & 3)) << 3));
}

// ======================= GEMM2: 256x256 8-wave counted-vmcnt pipeline =======================
// scores[b][1024,2048] = qe_b[1024,1216] @ ctx_b[2048,1216]^T, 3-term f16 split.
// K-tiles of 32; each tile = two 32KB halves: H0={Ah,Bh}, H1={Al,Bl}; halves cycle
// through 4 LDS slots. Steady state: 3 halves (12 loads) in flight, phase-top vmcnt(8).
#define T2K 38   // 1216/32
__global__ __launch_bounds__(512, 2) void gemm2_8p(
    const _Float16* __restrict__ Ahp, const _Float16* __restrict__ Alp,
    const _Float16* __restrict__ Bhp, const _Float16* __restrict__ Blp,
    float* __restrict__ Cf)
{
    const int t = threadIdx.x;
    const int bz = blockIdx.z;
    const _Float16* A_h = Ahp + bz * (1024L * 1216);
    const _Float16* A_l = Alp + bz * (1024L * 1216);
    const _Float16* B_h = Bhp + bz * (2048L * 1216);
    const _Float16* B_l = Blp + bz * (2048L * 1216);

    __shared__ __align__(16) _Float16 slots[4][2][256 * 32];   // 128 KiB

    const long row0 = (long)blockIdx.y * 256;   // O rows (exact: 4*256=1024)
    const long col0 = (long)blockIdx.x * 256;   // Q cols (exact: 8*256=2048)

    const int wid = t >> 6, lane = t & 63;
    const int wr = wid >> 2, wc = wid & 3;       // 2 x 4 waves -> per-wave 128x64
    const int fr = lane & 15, kslot = lane >> 4;

    f32x4 acc[8][4];
#pragma unroll
    for (int i = 0; i < 8; ++i)
#pragma unroll
        for (int j = 0; j < 4; ++j) acc[i][j] = (f32x4){0.f, 0.f, 0.f, 0.f};

    // prologue: stage halves 0 (hi t0), 1 (lo t0), 2 (hi t1)
    stage256(A_h, &slots[0][0][0], t, row0, 1216, 0);
    stage256(B_h, &slots[0][1][0], t, col0, 1216, 0);
    stage256(A_l, &slots[1][0][0], t, row0, 1216, 0);
    stage256(B_l, &slots[1][1][0], t, col0, 1216, 0);
    stage256(A_h, &slots[2][0][0], t, row0, 1216, 32);
    stage256(B_h, &slots[2][1][0], t, col0, 1216, 32);

    for (int tt = 0; tt < T2K; ++tt) {
        const int s0 = (2 * tt) & 3, s1 = (2 * tt + 1) & 3;

        // ======== phase H0 (half 2tt: hi pair) ========
        if (tt < T2K - 1) WAITV8(); else WAITV4();   // half 2tt resident (own share)
        __builtin_amdgcn_s_barrier();                 // collective residency + slot-readers done

        half8 a_h[8], b_h[4];
#pragma unroll
        for (int i = 0; i < 8; ++i) a_h[i] = frag(&slots[s0][0][0], wr * 128 + i * 16 + fr, kslot);
#pragma unroll
        for (int i = 0; i < 4; ++i) b_h[i] = frag(&slots[s0][1][0], wc * 64 + i * 16 + fr, kslot);

        if (tt < T2K - 1) {                           // stage half 2tt+3 = lo of tile tt+1
            const int k0 = (tt + 1) * 32, sl = (2 * tt + 3) & 3;
            stage256(A_l, &slots[sl][0][0], t, row0, 1216, k0);
            stage256(B_l, &slots[sl][1][0], t, col0, 1216, k0);
        }
        __builtin_amdgcn_s_barrier();
        WAITL0();
        __builtin_amdgcn_s_setprio(1);
#pragma unroll
        for (int mi = 0; mi < 8; ++mi)
#pragma unroll
            for (int ni = 0; ni < 4; ++ni)
                acc[mi][ni] = __builtin_amdgcn_mfma_f32_16x16x32_f16(a_h[mi], b_h[ni], acc[mi][ni], 0, 0, 0);
        __builtin_amdgcn_s_setprio(0);

        // ======== phase H1 (half 2tt+1: lo pair) ========
        if (tt < T2K - 1) WAITV8(); else WAITV0();
        __builtin_amdgcn_s_barrier();

        half8 a_l[8], b_l[4];
#pragma unroll
        for (int i = 0; i < 8; ++i) a_l[i] = frag(&slots[s1][0][0], wr * 128 + i * 16 + fr, kslot);
#pragma unroll
        for (int i = 0; i < 4; ++i) b_l[i] = frag(&slots[s1][1][0], wc * 64 + i * 16 + fr, kslot);

        if (tt < T2K - 2) {                           // stage half 2tt+4 = hi of tile tt+2
            const int k0 = (tt + 2) * 32, sl = (2 * tt + 4) & 3;
            stage256(A_h, &slots[sl][0][0], t, row0, 1216, k0);
            stage256(B_h, &slots[sl][1][0], t, col0, 1216, k0);
        }
        __builtin_amdgcn_s_barrier();
        WAITL0();
        __builtin_amdgcn_s_setprio(1);
#pragma unroll
        for (int mi = 0; mi < 8; ++mi)
#pragma unroll
            for (int ni = 0; ni < 4; ++ni) {
                acc[mi][ni] = __builtin_amdgcn_mfma_f32_16x16x32_f16(a_h[mi], b_l[ni], acc[mi][ni], 0, 0, 0);
                acc[mi][ni] = __builtin_amdgcn_mfma_f32_16x16x32_f16(a_l[mi], b_h[ni], acc[mi][ni], 0, 0, 0);
            }
        __builtin_amdgcn_s_setprio(0);
    }

    // epilogue: C/D layout col=lane&15, row=(lane>>4)*4+reg (m89-verified)
    const int r4 = (lane >> 4) * 4;
    float* C = Cf + bz * (1024L * 2048);
#pragma unroll
    for (int mi = 0; mi < 8; ++mi)
#pragma unroll
        for (int ni = 0; ni < 4; ++ni) {
            const long colg = col0 + wc * 64 + ni * 16 + fr;
#pragma unroll
            for (int r = 0; r < 4; ++r) {
                const long rowg = row0 + wr * 128 + mi * 16 + r4 + r;
                C[rowg * 2048 + colg] = acc[mi][ni][r];
            }
        }
}

// ======================= 128x128 2-phase GEMM (GEMM1 & GEMM3, unchanged from R5) =======================
template<bool SPLIT, bool OUT16>
__global__ __launch_bounds__(256) void gemm16(
    const _Float16* __restrict__ Ah, const _Float16* __restrict__ Al,
    const _Float16* __restrict__ Bh, const _Float16* __restrict__ Bl,
    float* __restrict__ Cf, _Float16* __restrict__ Ch, _Float16* __restrict__ Cl,
    int N, int K, int lda, int ldb, int ldc,
    long sA, long sB, long sC)
{
    const int t = threadIdx.x;
    const int bz = blockIdx.z;
    const _Float16* A_h = Ah + bz * sA;
    const _Float16* B_h = Bh + bz * sB;
    const _Float16* A_l = SPLIT ? (Al + bz * sA) : nullptr;
    const _Float16* B_l = SPLIT ? (Bl + bz * sB) : nullptr;

    __shared__ __align__(16) _Float16 sAh[2][128 * 32];
    __shared__ __align__(16) _Float16 sBh[2][128 * 32];
    __shared__ __align__(16) _Float16 sAl[SPLIT ? 2 : 1][SPLIT ? 128 * 32 : 8];
    __shared__ __align__(16) _Float16 sBl[SPLIT ? 2 : 1][SPLIT ? 128 * 32 : 8];

    const long row0 = (long)blockIdx.y * 128;
    const int  col0 = blockIdx.x * 128;

    const int wid = t >> 6, lane = t & 63;
    const int wm = (wid >> 1) * 64, wn = (wid & 1) * 64;
    const int fr = lane & 15, kslot = lane >> 4;

    f32x4 acc[4][4];
#pragma unroll
    for (int i = 0; i < 4; ++i)
#pragma unroll
        for (int j = 0; j < 4; ++j) acc[i][j] = (f32x4){0.f, 0.f, 0.f, 0.f};

    stage_tile(A_h, sAh[0], t, row0, row0 + 127, lda, 0);
    stage_tile(B_h, sBh[0], t, col0, N - 1, ldb, 0);
    if (SPLIT) {
        stage_tile(A_l, sAl[0], t, row0, row0 + 127, lda, 0);
        stage_tile(B_l, sBl[0], t, col0, N - 1, ldb, 0);
    }
    __syncthreads();

    int cur = 0;
    for (int k0 = 0; k0 < K; k0 += 32) {
        if (k0 + 32 < K) {
            const int nxt = cur ^ 1, kn = k0 + 32;
            stage_tile(A_h, sAh[nxt], t, row0, row0 + 127, lda, kn);
            stage_tile(B_h, sBh[nxt], t, col0, N - 1, ldb, kn);
            if (SPLIT) {
                stage_tile(A_l, sAl[nxt], t, row0, row0 + 127, lda, kn);
                stage_tile(B_l, sBl[nxt], t, col0, N - 1, ldb, kn);
            }
        }

        half8 a_h[4], b_h[4], a_l[4], b_l[4];
#pragma unroll
        for (int i = 0; i < 4; ++i) {
            a_h[i] = frag(sAh[cur], wm + i * 16 + fr, kslot);
            b_h[i] = frag(sBh[cur], wn + i * 16 + fr, kslot);
            if (SPLIT) {
                a_l[i] = frag(sAl[cur], wm + i * 16 + fr, kslot);
                b_l[i] = frag(sBl[cur], wn + i * 16 + fr, kslot);
            }
        }
#pragma unroll
        for (int mi = 0; mi < 4; ++mi)
#pragma unroll
            for (int ni = 0; ni < 4; ++ni) {
                acc[mi][ni] = __builtin_amdgcn_mfma_f32_16x16x32_f16(a_h[mi], b_h[ni], acc[mi][ni], 0, 0, 0);
                if (SPLIT) {
                    acc[mi][ni] = __builtin_amdgcn_mfma_f32_16x16x32_f16(a_h[mi], b_l[ni], acc[mi][ni], 0, 0, 0);
                    acc[mi][ni] = __builtin_amdgcn_mfma_f32_16x16x32_f16(a_l[mi], b_h[ni], acc[mi][ni], 0, 0, 0);
                }
            }

        __syncthreads();
        cur ^= 1;
    }

    const int r4 = (lane >> 4) * 4;
    float* C_f = OUT16 ? nullptr : (Cf + bz * sC);
#pragma unroll
    for (int mi = 0; mi < 4; ++mi)
#pragma unroll
        for (int ni = 0; ni < 4; ++ni) {
            const int colg = col0 + wn + ni * 16 + fr;
#pragma unroll
            for (int r = 0; r < 4; ++r) {
                const long rowg = row0 + wm + mi * 16 + r4 + r;
                const float v = acc[mi][ni][r];
                if (OUT16) {
                    if (colg < ldc) {
                        const float vv = (colg < N) ? v : 0.f;
                        const _Float16 hi = (_Float16)vv;
                        const _Float16 lo = (_Float16)(vv - (float)hi);
                        Ch[rowg * ldc + colg] = hi;
                        Cl[rowg * ldc + colg] = lo;
                    }
                } else {
                    if (colg < N) C_f[rowg * (long)ldc + colg] = v;
                }
            }
        }
}

// fused fp32 -> (hi,lo) f16 split for query_in and W
__global__ __launch_bounds__(256) void qw_cvt(
    const float* __restrict__ Q, _Float16* __restrict__ QH, _Float16* __restrict__ QL,
    const float* __restrict__ Wt, _Float16* __restrict__ WH, _Float16* __restrict__ WL)
{
    const long NQ = 8192L * 1024 / 4;
    const long NT = NQ + 1200L * 1024 / 4;
    for (long i = (long)blockIdx.x * 256 + threadIdx.x; i < NT; i += (long)gridDim.x * 256) {
        const float* src; _Float16 *dh, *dl; long j;
        if (i < NQ) { j = i; src = Q; dh = QH; dl = QL; }
        else        { j = i - NQ; src = Wt; dh = WH; dl = WL; }
        float4 v = *(const float4*)(src + j * 4);
        const _Float16 h0 = (_Float16)v.x, h1 = (_Float16)v.y, h2 = (_Float16)v.z, h3 = (_Float16)v.w;
        const _Float16 l0 = (_Float16)(v.x - (float)h0), l1 = (_Float16)(v.y - (float)h1);
        const _Float16 l2 = (_Float16)(v.z - (float)h2), l3 = (_Float16)(v.w - (float)h3);
        *(half4v*)(dh + j * 4) = (half4v){h0, h1, h2, h3};
        *(half4v*)(dl + j * 4) = (half4v){l0, l1, l2, l3};
    }
}

// fused ctx prep: one read of ctx f32 -> hi/lo split [8][2048][1216] + f16 transpose [8][1200][2048]
__global__ __launch_bounds__(256) void ctx_prep(const float* __restrict__ X,
    _Float16* __restrict__ H, _Float16* __restrict__ L, _Float16* __restrict__ T)
{
    const int b = blockIdx.z;
    const float* Xb = X + (long)b * 2048 * 1200;
    _Float16* Hb = H + (long)b * 2048 * 1216;
    _Float16* Lb = L + (long)b * 2048 * 1216;
    _Float16* Tb = T + (long)b * 1200 * 2048;
    __shared__ _Float16 tl[32][33];
    const int tx = threadIdx.x & 31, ty = threadIdx.x >> 5;
    const int s0 = blockIdx.x * 32, q0 = blockIdx.y * 32;
#pragma unroll
    for (int p = 0; p < 4; ++p) {
        const int q = q0 + ty + p * 8, s = s0 + tx;
        const float v = (s < 1200) ? Xb[(long)q * 1200 + s] : 0.f;
        const _Float16 hi = (_Float16)v;
        Hb[(long)q * 1216 + s] = hi;
        Lb[(long)q * 1216 + s] = (_Float16)(v - (float)hi);
        tl[tx][ty + p * 8] = hi;
    }
    __syncthreads();
#pragma unroll
    for (int p = 0; p < 4; ++p) {
        const int s = s0 + ty + p * 8;
        if (s < 1200) Tb[(long)s * 2048 + q0 + tx] = tl[ty + p * 8][tx];
    }
}

// in-place row softmax (2048) + f16 copy for GEMM3
__global__ __launch_bounds__(256) void softmax_k(float* __restrict__ w, _Float16* __restrict__ w16)
{
    float* p = w + (long)blockIdx.x * 2048;
    half4v* p16 = (half4v*)(w16 + (long)blockIdx.x * 2048);
    const int t = threadIdx.x;
    float4 v0 = ((const float4*)p)[t];
    float4 v1 = ((const float4*)p)[t + 256];

    float m = fmaxf(fmaxf(fmaxf(v0.x, v0.y), fmaxf(v0.z, v0.w)),
                    fmaxf(fmaxf(v1.x, v1.y), fmaxf(v1.z, v1.w)));
#pragma unroll
    for (int off = 1; off < 64; off <<= 1) m = fmaxf(m, __shfl_xor(m, off));
    __shared__ float redm[4], reds[4];
    const int wave = t >> 6, lane = t & 63;
    if (lane == 0) redm[wave] = m;
    __syncthreads();
    m = fmaxf(fmaxf(redm[0], redm[1]), fmaxf(redm[2], redm[3]));

    float e[8];
    e[0] = __expf(v0.x - m); e[1] = __expf(v0.y - m);
    e[2] = __expf(v0.z - m); e[3] = __expf(v0.w - m);
    e[4] = __expf(v1.x - m); e[5] = __expf(v1.y - m);
    e[6] = __expf(v1.z - m); e[7] = __expf(v1.w - m);

    float s = ((e[0] + e[1]) + (e[2] + e[3])) + ((e[4] + e[5]) + (e[6] + e[7]));
#pragma unroll
    for (int off = 1; off < 64; off <<= 1) s += __shfl_xor(s, off);
    if (lane == 0) reds[wave] = s;
    __syncthreads();
    s = (reds[0] + reds[1]) + (reds[2] + reds[3]);

    const float inv = 1.0f / s;
    float o0 = e[0] * inv, o1 = e[1] * inv, o2 = e[2] * inv, o3 = e[3] * inv;
    float o4 = e[4] * inv, o5 = e[5] * inv, o6 = e[6] * inv, o7 = e[7] * inv;
    ((float4*)p)[t]       = make_float4(o0, o1, o2, o3);
    ((float4*)p)[t + 256] = make_float4(o4, o5, o6, o7);
    p16[t]       = (half4v){(_Float16)o0, (_Float16)o1, (_Float16)o2, (_Float16)o3};
    p16[t + 256] = (half4v){(_Float16)o4, (_Float16)o5, (_Float16)o6, (_Float16)o7};
}

extern "C" void kernel_launch(void* const* d_in, const int* in_sizes, int n_in,
                              void* d_out, int out_size, void* d_ws, size_t ws_size,
                              hipStream_t stream)
{
    const float* query_in = (const float*)d_in[0]; // [8,1024,1024]
    const float* context  = (const float*)d_in[1]; // [8,2048,1200]
    const float* W        = (const float*)d_in[2]; // [1200,1024]

    float* mix    = (float*)d_out;                 // [8,1024,1200]
    float* scores = (float*)d_out + 9830400LL;     // [8,1024,2048] -> softmax in place

    // ws layout (halfs); ~220 MB
    _Float16* qh  = (_Float16*)d_ws;               // query_in hi  [8192,1024]
    _Float16* ql  = qh  + 8388608;                 // query_in lo
    _Float16* wh  = ql  + 8388608;                 // W hi         [1200,1024]
    _Float16* wl  = wh  + 1228800;                 // W lo
    _Float16* ch  = wl  + 1228800;                 // ctx hi       [16384,1216] (zero-pad 1200..1215)
    _Float16* cl  = ch  + 19922944;                // ctx lo
    _Float16* ct  = cl  + 19922944;                // ctxT f16     [8][1200][2048]
    _Float16* qeh = ct  + 19660800;                // query hi     [8192,1216]
    _Float16* qel = qeh + 9961472;                 // query lo
    _Float16* w16 = qel + 9961472;                 // weights f16  [8192,2048]

    dim3 blk(256);

    qw_cvt<<<2400, blk, 0, stream>>>(query_in, qh, ql, W, wh, wl);
    ctx_prep<<<dim3(38, 64, 8), blk, 0, stream>>>(context, ch, cl, ct);

    // GEMM1: query(hi/lo)[8192,1216] = qin[8192,1024] @ W[1200,1024]^T  (split, out f16 pair)
    gemm16<true, true><<<dim3(10, 64, 1), blk, 0, stream>>>(
        qh, ql, wh, wl, nullptr, qeh, qel,
        1200, 1024, 1024, 1024, 1216, 0, 0, 0);

    // GEMM2: scores[b][1024,2048] = qe_b[1024,1216] @ ctx_b[2048,1216]^T  (split, 8-wave pipeline)
    gemm2_8p<<<dim3(8, 4, 8), dim3(512), 0, stream>>>(qeh, qel, ch, cl, scores);

    softmax_k<<<dim3(8192), blk, 0, stream>>>(scores, w16);

    // GEMM3: mix[b][1024,1200] = w16_b[1024,2048] @ ctxT_b[1200,2048]^T  (pure f16, out f32)
    gemm16<false, false><<<dim3(10, 8, 8), blk, 0, stream>>>(
        w16, nullptr, ct, nullptr, mix, nullptr, nullptr,
        1200, 2048, 2048, 2048, 1200, 1024L * 2048, 1200L * 2048, 1024L * 1200);
}